// Round 5
// baseline (324.322 us; speedup 1.0000x reference)
//
#include <hip/hip_runtime.h>
#include <math.h>

// MultiHeadSelfAttention: B=2, S=2048, E=1024, H=16, D=64
// Reference computes Q@V^T (source bug, K unused) -> softmax -> @V.
// Round 5: T14 async staging (proj + attn), MFMA row-sum (ones-row tile),
// exp2-domain softmax, defer-max, coalesced VT epilogue via LDS bounce.

constexpr int BATCH = 2;
constexpr int SEQ   = 2048;
constexpr int EMB   = 1024;
constexpr int NHEAD = 16;
constexpr int HDIM  = 64;
constexpr int HID   = 1024;

typedef __attribute__((ext_vector_type(8))) _Float16 half8;
typedef __attribute__((ext_vector_type(4))) float    f32x4;

#define MFMA16(a, b, c) __builtin_amdgcn_mfma_f32_16x16x32_f16((a), (b), (c), 0, 0, 0)

// LDS leading dim (halves): 80 -> 40 dwords/row == 8 mod 32 -> frag reads
// (rows l15, 16B at 4*l4 dwords) hit banks 8*l15+4*l4: 2-way = free.
constexpr int LDT = 80;

// scores scale folded with log2(e): softmax computed in exp2 domain
// (identical values: 2^(x*log2e) == e^x).
#define QK_SCALE 0.18033688011112042f
// defer-max threshold in log2 units: P <= 2^11 = 2048, safe in fp16.
#define LOG2_THR 11.0f

__device__ __forceinline__ _Float16 f2h(float f) { return (_Float16)f; }

// ---------------------------------------------------------------------------
// conv_x: fp32 -> fp16 elementwise (X)
// ---------------------------------------------------------------------------
__global__ __launch_bounds__(256) void conv_x_kernel(
    const float* __restrict__ X, _Float16* __restrict__ Xb, int n4)
{
    union Pack { uint2 q; _Float16 e[4]; };
    int idx = blockIdx.x * 256 + threadIdx.x;
    int stride = gridDim.x * 256;
    for (int i = idx; i < n4; i += stride) {
        float4 v = ((const float4*)X)[i];
        Pack p;
        p.e[0] = f2h(v.x); p.e[1] = f2h(v.y);
        p.e[2] = f2h(v.z); p.e[3] = f2h(v.w);
        ((uint2*)Xb)[i] = p.q;
    }
}

// ---------------------------------------------------------------------------
// conv_wt: W [K=1024][N=1024] fp32  ->  WT [N][K] fp16 (transpose via LDS)
// ---------------------------------------------------------------------------
__global__ __launch_bounds__(256) void conv_wt_kernel(
    const float* __restrict__ W, _Float16* __restrict__ WT)
{
    __shared__ _Float16 T[64 * 68];
    const int tid = threadIdx.x;
    const int n0 = blockIdx.x * 64;
    const int k0 = blockIdx.y * 64;

    #pragma unroll
    for (int i = 0; i < 4; ++i) {
        const int u = tid + i * 256;
        const int r = u >> 4;              // k row
        const int c4 = (u & 15) << 2;      // n col
        const float4 v = *(const float4*)&W[(size_t)(k0 + r) * HID + n0 + c4];
        T[r * 68 + c4 + 0] = f2h(v.x);
        T[r * 68 + c4 + 1] = f2h(v.y);
        T[r * 68 + c4 + 2] = f2h(v.z);
        T[r * 68 + c4 + 3] = f2h(v.w);
    }
    __syncthreads();

    union Pack { uint4 q; _Float16 e[8]; };
    #pragma unroll
    for (int i = 0; i < 2; ++i) {
        const int u = tid + i * 256;
        const int n = u >> 3;
        const int kc = (u & 7) << 3;
        Pack p;
        #pragma unroll
        for (int j = 0; j < 8; ++j) p.e[j] = T[(kc + j) * 68 + n];
        *(uint4*)&WT[(size_t)(n0 + n) * EMB + k0 + kc] = p.q;
    }
}

// ---------------------------------------------------------------------------
// proj: Q = Xb@WTq^T + bq, V = Xb@WTv^T + bv
// Outputs: Qo, Vo fp16 [B][H][S][D]; VTo fp16 [B][H][D][S] (for attn PV).
// 128x64 tile, 4 waves, BK=64, mfma 16x16x32 f16.
// T14: global loads for k+1 issued into regs before compute of k; ds_write
// between the two barriers. VT stores coalesced via LDS bounce.
// ---------------------------------------------------------------------------
__global__ __launch_bounds__(256) void proj_kernel(
    const _Float16* __restrict__ Xb, const _Float16* __restrict__ WTq,
    const _Float16* __restrict__ WTv, const float* __restrict__ bq,
    const float* __restrict__ bv, _Float16* __restrict__ Qo,
    _Float16* __restrict__ Vo, _Float16* __restrict__ VTo)
{
    __shared__ __align__(16) _Float16 Xs[128 * LDT];
    __shared__ __align__(16) _Float16 Wqs[64 * LDT];
    __shared__ __align__(16) _Float16 Wvs[64 * LDT];

    const int tid  = threadIdx.x;
    const int lane = tid & 63;
    const int w    = tid >> 6;
    // XCD-contiguous remap: 512 blocks, 64 per XCD, h-major.
    const int wg   = blockIdx.x;
    const int nid  = (wg & 7) * 64 + (wg >> 3);
    const int h    = nid >> 5;
    const int m0   = (nid & 31) * 128;
    const int n0   = h * HDIM;
    const int l15  = lane & 15;
    const int l4   = lane >> 4;

    f32x4 aq[2][4], av[2][4];
    #pragma unroll
    for (int mt = 0; mt < 2; ++mt)
        #pragma unroll
        for (int nt = 0; nt < 4; ++nt) {
            aq[mt][nt] = f32x4{0.f, 0.f, 0.f, 0.f};
            av[mt][nt] = f32x4{0.f, 0.f, 0.f, 0.f};
        }

    uint4 rx[4], rwq[2], rwv[2];
    auto issueP = [&](int k0) {
        #pragma unroll
        for (int i = 0; i < 4; ++i) {
            const int u = tid + i * 256, r = u >> 3, c8 = (u & 7) << 3;
            rx[i] = *(const uint4*)&Xb[(size_t)(m0 + r) * EMB + k0 + c8];
        }
        #pragma unroll
        for (int i = 0; i < 2; ++i) {
            const int u = tid + i * 256, r = u >> 3, c8 = (u & 7) << 3;
            rwq[i] = *(const uint4*)&WTq[(size_t)(n0 + r) * EMB + k0 + c8];
            rwv[i] = *(const uint4*)&WTv[(size_t)(n0 + r) * EMB + k0 + c8];
        }
    };
    auto writeP = [&]() {
        #pragma unroll
        for (int i = 0; i < 4; ++i) {
            const int u = tid + i * 256, r = u >> 3, c8 = (u & 7) << 3;
            *(uint4*)&Xs[r * LDT + c8] = rx[i];
        }
        #pragma unroll
        for (int i = 0; i < 2; ++i) {
            const int u = tid + i * 256, r = u >> 3, c8 = (u & 7) << 3;
            *(uint4*)&Wqs[r * LDT + c8] = rwq[i];
            *(uint4*)&Wvs[r * LDT + c8] = rwv[i];
        }
    };

    issueP(0);
    writeP();
    __syncthreads();

    for (int k0 = 0; k0 < EMB; k0 += 64) {
        if (k0 + 64 < EMB) issueP(k0 + 64);   // overlap with compute below

        __builtin_amdgcn_s_setprio(1);
        #pragma unroll
        for (int kd = 0; kd < 2; ++kd) {
            const int ko = kd * 32 + l4 * 8;
            half8 xa0 = *(const half8*)&Xs[(w * 32 + l15) * LDT + ko];
            half8 xa1 = *(const half8*)&Xs[(w * 32 + 16 + l15) * LDT + ko];
            #pragma unroll
            for (int nt = 0; nt < 4; ++nt) {
                half8 wq = *(const half8*)&Wqs[(nt * 16 + l15) * LDT + ko];
                half8 wv = *(const half8*)&Wvs[(nt * 16 + l15) * LDT + ko];
                aq[0][nt] = MFMA16(xa0, wq, aq[0][nt]);
                aq[1][nt] = MFMA16(xa1, wq, aq[1][nt]);
                av[0][nt] = MFMA16(xa0, wv, av[0][nt]);
                av[1][nt] = MFMA16(xa1, wv, av[1][nt]);
            }
        }
        __builtin_amdgcn_s_setprio(0);
        __syncthreads();
        if (k0 + 64 < EMB) writeP();
        __syncthreads();
    }

    // ---- epilogue ----
    constexpr int LV = 65;                 // odd stride: VT column reads ~2-4 way
    _Float16* Vlds = Xs;                   // reuse (128*65 <= 128*80)
    const int bb = m0 >> 11;
    const int s_base = m0 & (SEQ - 1);
    const int bh = bb * NHEAD + h;

    #pragma unroll
    for (int nt = 0; nt < 4; ++nt) {
        const int d = nt * 16 + l15;
        const float bqv = bq[n0 + d];
        const float bvv = bv[n0 + d];
        #pragma unroll
        for (int mt = 0; mt < 2; ++mt)
            #pragma unroll
            for (int r = 0; r < 4; ++r) {
                const int sl = w * 32 + mt * 16 + l4 * 4 + r;
                const int s  = s_base + sl;
                const _Float16 qh = f2h(aq[mt][nt][r] + bqv);
                const _Float16 vh = f2h(av[mt][nt][r] + bvv);
                Qo[((size_t)bh * SEQ + s) * HDIM + d] = qh;
                Vo[((size_t)bh * SEQ + s) * HDIM + d] = vh;
                Vlds[sl * LV + d] = vh;
            }
    }
    __syncthreads();

    union PK { uint4 q; _Float16 e[8]; };
    #pragma unroll
    for (int i = 0; i < 4; ++i) {
        const int c  = tid + i * 256;      // 0..1023 chunks of 8 s-values
        const int d  = c >> 4;             // 0..63
        const int sc = (c & 15) << 3;      // 0..120
        PK p;
        #pragma unroll
        for (int j = 0; j < 8; ++j) p.e[j] = Vlds[(sc + j) * LV + d];
        *(uint4*)&VTo[((size_t)bh * HDIM + d) * SEQ + s_base + sc] = p.q;
    }
}

// ---------------------------------------------------------------------------
// attn: per (b,h) flash attention. scores = Q@V^T/8 (source bug), softmax,
// @V. 64 Q-rows/block, 4 waves x 16 rows, KV tiles of 64.
// exp2-domain online softmax; denominator via 5th MFMA against a ones-row
// tile (VTs rows 64..79); defer-max; T14 split staging.
// ---------------------------------------------------------------------------
__global__ __launch_bounds__(256) void attn_kernel(
    const _Float16* __restrict__ Qw, const _Float16* __restrict__ Vw,
    const _Float16* __restrict__ VTw, float* __restrict__ out)
{
    __shared__ __align__(16) _Float16 PQs[64 * LDT];  // Q then P (overlay)
    __shared__ __align__(16) _Float16 Vs[64 * LDT];
    __shared__ __align__(16) _Float16 VTs[80 * LDT];  // rows 64..79: ones tile

    const int tid  = threadIdx.x;
    const int lane = tid & 63;
    const int w    = tid >> 6;
    const int l15  = lane & 15;
    const int l4   = lane >> 4;
    // XCD-contiguous remap: 1024 blocks, 128/XCD.
    const int wg = blockIdx.x;
    const int nw = (wg & 7) * 128 + (wg >> 3);
    const int bh = nw >> 5;
    const int qb = nw & 31;
    const int b  = bh >> 4;
    const int h  = bh & (NHEAD - 1);
    const int s0 = qb * 64;

    const _Float16* Qp  = Qw  + (size_t)bh * SEQ * HDIM;
    const _Float16* Vp  = Vw  + (size_t)bh * SEQ * HDIM;
    const _Float16* VTp = VTw + (size_t)bh * HDIM * SEQ;

    // T14 split staging: issue loads early, LDS-write late.
    uint4 rv[2], rvt[2];
    auto issueV = [&](int t) {
        #pragma unroll
        for (int i = 0; i < 2; ++i) {
            const int u = tid + i * 256, r = u >> 3, c8 = (u & 7) << 3;
            rv[i]  = *(const uint4*)&Vp[(size_t)(t * 64 + r) * HDIM + c8];
            rvt[i] = *(const uint4*)&VTp[(size_t)r * SEQ + t * 64 + c8];
        }
    };
    auto writeV = [&]() {
        #pragma unroll
        for (int i = 0; i < 2; ++i) {
            const int u = tid + i * 256, r = u >> 3, c8 = (u & 7) << 3;
            *(uint4*)&Vs[r * LDT + c8]  = rv[i];
            *(uint4*)&VTs[r * LDT + c8] = rvt[i];
        }
    };

    // Q tile -> PQs
    #pragma unroll
    for (int i = 0; i < 2; ++i) {
        const int u = tid + i * 256, r = u >> 3, c8 = (u & 7) << 3;
        *(uint4*)&PQs[r * LDT + c8] =
            *(const uint4*)&Qp[(size_t)(s0 + r) * HDIM + c8];
    }
    // ones tile: row 64 (k cols) = 1, rows 65..79 = 0 (written once)
    #pragma unroll
    for (int i = 0; i < 5; ++i) {
        const int idx = tid + i * 256;
        if (idx < 16 * LDT)
            VTs[64 * LDT + idx] = (idx < LDT) ? (_Float16)1.0f : (_Float16)0.0f;
    }
    issueV(0);
    writeV();
    __syncthreads();

    // hoist Q A-frags (own 16 rows only; those rows later hold this wave's P)
    const half8 qa0 = *(const half8*)&PQs[(w * 16 + l15) * LDT + l4 * 8];
    const half8 qa1 = *(const half8*)&PQs[(w * 16 + l15) * LDT + 32 + l4 * 8];

    f32x4 acc_o[5];   // [0..3]: output d-tiles; [4]: softmax denominator
    #pragma unroll
    for (int dt = 0; dt < 5; ++dt) acc_o[dt] = f32x4{0.f, 0.f, 0.f, 0.f};
    float m_i[4] = {-INFINITY, -INFINITY, -INFINITY, -INFINITY};

    const int chi  = l15 >> 3;
    const int hl   = l15 & 7;
    const int rkey = l15 & 7;

    for (int t = 0; t < SEQ / 64; ++t) {
        // ---- QK^T ----
        f32x4 acc_s[4];
        #pragma unroll
        for (int nt = 0; nt < 4; ++nt) acc_s[nt] = f32x4{0.f, 0.f, 0.f, 0.f};
        __builtin_amdgcn_s_setprio(1);
        #pragma unroll
        for (int nt = 0; nt < 4; ++nt) {
            half8 vb0 = *(const half8*)&Vs[(nt * 16 + l15) * LDT + l4 * 8];
            half8 vb1 = *(const half8*)&Vs[(nt * 16 + l15) * LDT + 32 + l4 * 8];
            acc_s[nt] = MFMA16(qa0, vb0, acc_s[nt]);
            acc_s[nt] = MFMA16(qa1, vb1, acc_s[nt]);
        }
        __builtin_amdgcn_s_setprio(0);

        if (t + 1 < SEQ / 64) issueV(t + 1);   // latency hidden by softmax+PV

        // ---- softmax (exp2 domain, defer-max) ----
        float sc4[4][4], mloc[4];
        int needf = 0;
        #pragma unroll
        for (int r = 0; r < 4; ++r) {
            sc4[r][0] = acc_s[0][r] * QK_SCALE;
            sc4[r][1] = acc_s[1][r] * QK_SCALE;
            sc4[r][2] = acc_s[2][r] * QK_SCALE;
            sc4[r][3] = acc_s[3][r] * QK_SCALE;
            float ml = fmaxf(fmaxf(sc4[r][0], sc4[r][1]),
                             fmaxf(sc4[r][2], sc4[r][3]));
            #pragma unroll
            for (int off = 1; off < 16; off <<= 1)
                ml = fmaxf(ml, __shfl_xor(ml, off));
            mloc[r] = ml;
            needf |= (ml > m_i[r] + LOG2_THR) ? 1 : 0;
        }
        if (__any(needf)) {
            #pragma unroll
            for (int r = 0; r < 4; ++r) {
                const float mnew = fmaxf(m_i[r], mloc[r]);
                const float corr = __builtin_amdgcn_exp2f(m_i[r] - mnew);
                m_i[r] = mnew;
                #pragma unroll
                for (int dt = 0; dt < 5; ++dt) acc_o[dt][r] *= corr;
            }
        }
        #pragma unroll
        for (int r = 0; r < 4; ++r) {
            const float p0 = __builtin_amdgcn_exp2f(sc4[r][0] - m_i[r]);
            const float p1 = __builtin_amdgcn_exp2f(sc4[r][1] - m_i[r]);
            const float p2 = __builtin_amdgcn_exp2f(sc4[r][2] - m_i[r]);
            const float p3 = __builtin_amdgcn_exp2f(sc4[r][3] - m_i[r]);
            const int key = (l4 * 4 + r) & 7;
            _Float16* pr = &PQs[(w * 16 + l4 * 4 + r) * LDT];
            pr[(((0 + chi) ^ key) << 3) + hl] = f2h(p0);
            pr[(((2 + chi) ^ key) << 3) + hl] = f2h(p1);
            pr[(((4 + chi) ^ key) << 3) + hl] = f2h(p2);
            pr[(((6 + chi) ^ key) << 3) + hl] = f2h(p3);
        }

        // ---- PV (+ denominator via ones tile, dt==4) ----
        const _Float16* prd = &PQs[(w * 16 + l15) * LDT];
        half8 pa0 = *(const half8*)&prd[((l4 ^ rkey) << 3)];
        half8 pa1 = *(const half8*)&prd[(((4 + l4) ^ rkey) << 3)];
        __builtin_amdgcn_s_setprio(1);
        #pragma unroll
        for (int dt = 0; dt < 5; ++dt) {
            half8 vt0 = *(const half8*)&VTs[(dt * 16 + l15) * LDT + l4 * 8];
            half8 vt1 = *(const half8*)&VTs[(dt * 16 + l15) * LDT + 32 + l4 * 8];
            acc_o[dt] = MFMA16(pa0, vt0, acc_o[dt]);
            acc_o[dt] = MFMA16(pa1, vt1, acc_o[dt]);
        }
        __builtin_amdgcn_s_setprio(0);

        __syncthreads();                   // all reads of Vs/VTs done
        if (t + 1 < SEQ / 64) writeV();    // fast LDS write (data already in regs)
        __syncthreads();
    }

    // ---- epilogue: normalize + store fp32 [B][S][H*D] ----
    // denominator lives in col 0 of the ones-tile result: lanes l15==0.
    #pragma unroll
    for (int r = 0; r < 4; ++r) {
        const float ls  = __shfl(acc_o[4][r], (lane & 48));
        const float inv = 1.f / ls;
        const int s = s0 + w * 16 + l4 * 4 + r;
        float* op = &out[((size_t)(b * SEQ + s)) * HID + h * HDIM + l15];
        op[ 0] = acc_o[0][r] * inv;
        op[16] = acc_o[1][r] * inv;
        op[32] = acc_o[2][r] * inv;
        op[48] = acc_o[3][r] * inv;
    }
}

// ---------------------------------------------------------------------------
extern "C" void kernel_launch(void* const* d_in, const int* in_sizes, int n_in,
                              void* d_out, int out_size, void* d_ws, size_t ws_size,
                              hipStream_t stream) {
    (void)in_sizes; (void)n_in; (void)out_size; (void)ws_size;
    const float* X  = (const float*)d_in[0];
    const float* Wq = (const float*)d_in[1];
    const float* bq = (const float*)d_in[2];
    // d_in[3] = Wk, d_in[4] = bk: unused by the reference output (source bug)
    const float* Wv = (const float*)d_in[5];
    const float* bv = (const float*)d_in[6];
    float* outp = (float*)d_out;

    char* ws = (char*)d_ws;
    _Float16* Xb  = (_Float16*)(ws);                    //  8 MB [4096][1024]
    _Float16* WTq = (_Float16*)(ws + (8u  << 20));      //  2 MB [N][K]
    _Float16* WTv = (_Float16*)(ws + (10u << 20));      //  2 MB
    _Float16* Qb  = (_Float16*)(ws + (12u << 20));      //  8 MB [B][H][S][D]
    _Float16* Vb  = (_Float16*)(ws + (20u << 20));      //  8 MB [B][H][S][D]
    _Float16* VTb = (_Float16*)(ws + (28u << 20));      //  8 MB [B][H][D][S]

    conv_x_kernel<<<1024, 256, 0, stream>>>(X, Xb, (BATCH * SEQ * EMB) / 4);
    conv_wt_kernel<<<dim3(16, 16), 256, 0, stream>>>(Wq, WTq);
    conv_wt_kernel<<<dim3(16, 16), 256, 0, stream>>>(Wv, WTv);
    proj_kernel<<<512, 256, 0, stream>>>(Xb, WTq, WTv, bq, bv, Qb, Vb, VTb);
    attn_kernel<<<1024, 256, 0, stream>>>(Qb, Vb, VTb, outp);
}

// Round 6
// 228.961 us; speedup vs baseline: 1.4165x; 1.4165x over previous
//
#include <hip/hip_runtime.h>
#include <math.h>

// MultiHeadSelfAttention: B=2, S=2048, E=1024, H=16, D=64
// Reference computes Q@V^T (source bug, K unused) -> softmax -> @V.
// Round 6: revert T14 reg-staging (R5 scratch-spill regression: WRITE_SIZE
// 16->86MB), keep exp2/ones-tile/defer-max softmax, Q pre-scaled in proj,
// conv_x fused into proj (fp32 X read + inline cvt), proj BM=64 m-major
// XCD remap, merged conv_wt.

constexpr int BATCH = 2;
constexpr int SEQ   = 2048;
constexpr int EMB   = 1024;
constexpr int NHEAD = 16;
constexpr int HDIM  = 64;
constexpr int HID   = 1024;

typedef __attribute__((ext_vector_type(8))) _Float16 half8;
typedef __attribute__((ext_vector_type(4))) float    f32x4;

#define MFMA16(a, b, c) __builtin_amdgcn_mfma_f32_16x16x32_f16((a), (b), (c), 0, 0, 0)

// LDS leading dim (halves): 80 -> 40 dwords/row == 8 mod 32 -> frag reads
// (rows l15, 16B at 4*l4 dwords) hit banks 8*l15+4*l4: 2-way = free.
constexpr int LDT = 80;

// 1/sqrt(64) * log2(e): scores land directly in exp2 domain. Folded into Q
// at proj epilogue (pre-scaled Q in workspace).
#define QK_SCALE 0.18033688011112042f
// defer-max threshold in log2 units: P <= 2^11 = 2048, safe in fp16.
#define LOG2_THR 11.0f

__device__ __forceinline__ _Float16 f2h(float f) { return (_Float16)f; }

// ---------------------------------------------------------------------------
// conv_wt: W [K][N] fp32 -> WT [N][K] fp16, both weights in one launch (z).
// ---------------------------------------------------------------------------
__global__ __launch_bounds__(256) void conv_wt_kernel(
    const float* __restrict__ W0, _Float16* __restrict__ WT0,
    const float* __restrict__ W1, _Float16* __restrict__ WT1)
{
    const float*  W  = blockIdx.z ? W1  : W0;
    _Float16*     WT = blockIdx.z ? WT1 : WT0;
    __shared__ _Float16 T[64 * 68];
    const int tid = threadIdx.x;
    const int n0 = blockIdx.x * 64;
    const int k0 = blockIdx.y * 64;

    #pragma unroll
    for (int i = 0; i < 4; ++i) {
        const int u = tid + i * 256;
        const int r = u >> 4;              // k row
        const int c4 = (u & 15) << 2;      // n col
        const float4 v = *(const float4*)&W[(size_t)(k0 + r) * HID + n0 + c4];
        T[r * 68 + c4 + 0] = f2h(v.x);
        T[r * 68 + c4 + 1] = f2h(v.y);
        T[r * 68 + c4 + 2] = f2h(v.z);
        T[r * 68 + c4 + 3] = f2h(v.w);
    }
    __syncthreads();

    union Pack { uint4 q; _Float16 e[8]; };
    #pragma unroll
    for (int i = 0; i < 2; ++i) {
        const int u = tid + i * 256;
        const int n = u >> 3;
        const int kc = (u & 7) << 3;
        Pack p;
        #pragma unroll
        for (int j = 0; j < 8; ++j) p.e[j] = T[(kc + j) * 68 + n];
        *(uint4*)&WT[(size_t)(n0 + n) * EMB + k0 + kc] = p.q;
    }
}

// ---------------------------------------------------------------------------
// proj: Q = (X@WTq^T + bq)*QK_SCALE, V = X@WTv^T + bv
// X read as fp32, converted during LDS staging (no conv_x pass).
// Outputs: Qo (pre-scaled), Vo fp16 [B][H][S][D]; VTo fp16 [B][H][D][S].
// BM=64, 4 waves x 16 rows, BK=64, grid 1024 (4 blocks/CU), m-major XCD
// remap (X panels L2-resident; W rides L3).
// ---------------------------------------------------------------------------
__global__ __launch_bounds__(256) void proj_kernel(
    const float* __restrict__ X, const _Float16* __restrict__ WTq,
    const _Float16* __restrict__ WTv, const float* __restrict__ bq,
    const float* __restrict__ bv, _Float16* __restrict__ Qo,
    _Float16* __restrict__ Vo, _Float16* __restrict__ VTo)
{
    __shared__ __align__(16) _Float16 Xs[64 * LDT];
    __shared__ __align__(16) _Float16 Wqs[64 * LDT];
    __shared__ __align__(16) _Float16 Wvs[64 * LDT];

    const int tid  = threadIdx.x;
    const int lane = tid & 63;
    const int w    = tid >> 6;
    const int l15  = lane & 15;
    const int l4   = lane >> 4;
    // m-major XCD remap: XCD x gets mblk in [8x, 8x+8), all 16 heads ->
    // 8 X panels (2MB fp32) L2-resident, reused by 16 head-blocks.
    const int wg   = blockIdx.x;
    const int nid  = (wg & 7) * 128 + (wg >> 3);
    const int mblk = nid >> 4;
    const int h    = nid & 15;
    const int m0   = mblk * 64;
    const int n0   = h * HDIM;

    f32x4 aq[4], av[4];
    #pragma unroll
    for (int nt = 0; nt < 4; ++nt) {
        aq[nt] = f32x4{0.f, 0.f, 0.f, 0.f};
        av[nt] = f32x4{0.f, 0.f, 0.f, 0.f};
    }

    for (int k0 = 0; k0 < EMB; k0 += 64) {
        // X tile 64x64 fp32 -> fp16 LDS (inline convert)
        #pragma unroll
        for (int i = 0; i < 4; ++i) {
            const int u = tid + i * 256;       // float4 index
            const int r = u >> 4;              // 0..63
            const int c4 = (u & 15) << 2;      // 0..60
            const float4 v = *(const float4*)&X[(size_t)(m0 + r) * EMB + k0 + c4];
            Xs[r * LDT + c4 + 0] = f2h(v.x);
            Xs[r * LDT + c4 + 1] = f2h(v.y);
            Xs[r * LDT + c4 + 2] = f2h(v.z);
            Xs[r * LDT + c4 + 3] = f2h(v.w);
        }
        // W tiles (already fp16 [N][K])
        #pragma unroll
        for (int i = 0; i < 2; ++i) {
            const int u = tid + i * 256;
            const int r = u >> 3;
            const int c8 = (u & 7) << 3;
            *(uint4*)&Wqs[r * LDT + c8] =
                *(const uint4*)&WTq[(size_t)(n0 + r) * EMB + k0 + c8];
            *(uint4*)&Wvs[r * LDT + c8] =
                *(const uint4*)&WTv[(size_t)(n0 + r) * EMB + k0 + c8];
        }
        __syncthreads();

        __builtin_amdgcn_s_setprio(1);
        #pragma unroll
        for (int kd = 0; kd < 2; ++kd) {
            const int ko = kd * 32 + l4 * 8;
            half8 xa = *(const half8*)&Xs[(w * 16 + l15) * LDT + ko];
            #pragma unroll
            for (int nt = 0; nt < 4; ++nt) {
                half8 wq = *(const half8*)&Wqs[(nt * 16 + l15) * LDT + ko];
                half8 wv = *(const half8*)&Wvs[(nt * 16 + l15) * LDT + ko];
                aq[nt] = MFMA16(xa, wq, aq[nt]);
                av[nt] = MFMA16(xa, wv, av[nt]);
            }
        }
        __builtin_amdgcn_s_setprio(0);
        __syncthreads();
    }

    // ---- epilogue: bias, Q pre-scale, V + coalesced VT via LDS bounce ----
    constexpr int LV = 65;
    _Float16* Vlds = Xs;                   // 64*65 <= 64*80
    const int bb = m0 >> 11;
    const int sb = m0 & (SEQ - 1);
    const int bh = bb * NHEAD + h;

    #pragma unroll
    for (int nt = 0; nt < 4; ++nt) {
        const int d = nt * 16 + l15;
        const float bqv = bq[n0 + d];
        const float bvv = bv[n0 + d];
        #pragma unroll
        for (int r = 0; r < 4; ++r) {
            const int sl = w * 16 + l4 * 4 + r;
            const int s  = sb + sl;
            const _Float16 vh = f2h(av[nt][r] + bvv);
            Qo[((size_t)bh * SEQ + s) * HDIM + d] =
                f2h((aq[nt][r] + bqv) * QK_SCALE);
            Vo[((size_t)bh * SEQ + s) * HDIM + d] = vh;
            Vlds[sl * LV + d] = vh;
        }
    }
    __syncthreads();

    union PK { uint4 q; _Float16 e[8]; };
    #pragma unroll
    for (int i = 0; i < 2; ++i) {
        const int c  = tid + i * 256;      // 0..511: 64 d x 8 s-chunks
        const int d  = c >> 3;
        const int sc = (c & 7) << 3;
        PK p;
        #pragma unroll
        for (int j = 0; j < 8; ++j) p.e[j] = Vlds[(sc + j) * LV + d];
        *(uint4*)&VTo[((size_t)bh * HDIM + d) * SEQ + sb + sc] = p.q;
    }
}

// ---------------------------------------------------------------------------
// attn: per (b,h) flash attention. scores = Q@V^T (Q pre-scaled, exp2
// domain), online softmax with defer-max, denominator via ones-row tile
// (5th PV MFMA). 64 Q-rows/block, 4 waves, KV tiles of 64. Direct staging
// (load+ds_write between barriers; no cross-phase reg holding).
// ---------------------------------------------------------------------------
__global__ __launch_bounds__(256) void attn_kernel(
    const _Float16* __restrict__ Qw, const _Float16* __restrict__ Vw,
    const _Float16* __restrict__ VTw, float* __restrict__ out)
{
    __shared__ __align__(16) _Float16 PQs[64 * LDT];  // Q then P (overlay)
    __shared__ __align__(16) _Float16 Vs[64 * LDT];
    __shared__ __align__(16) _Float16 VTs[80 * LDT];  // rows 64..79: ones tile

    const int tid  = threadIdx.x;
    const int lane = tid & 63;
    const int w    = tid >> 6;
    const int l15  = lane & 15;
    const int l4   = lane >> 4;
    // bh-major XCD remap: 4 heads' V/VT streams (4MB) per XCD L2.
    const int wg = blockIdx.x;
    const int nw = (wg & 7) * 128 + (wg >> 3);
    const int bh = nw >> 5;
    const int qb = nw & 31;
    const int b  = bh >> 4;
    const int h  = bh & (NHEAD - 1);
    const int s0 = qb * 64;

    const _Float16* Qp  = Qw  + (size_t)bh * SEQ * HDIM;
    const _Float16* Vp  = Vw  + (size_t)bh * SEQ * HDIM;
    const _Float16* VTp = VTw + (size_t)bh * HDIM * SEQ;

    // direct staging: all 4 loads issued, then 4 LDS writes (single latency
    // exposure, no registers held across compute phases)
    auto stageV = [&](int t) {
        const int u0 = tid,       r0 = u0 >> 3, c0 = (u0 & 7) << 3;
        const int u1 = tid + 256, r1 = u1 >> 3, c1 = (u1 & 7) << 3;
        uint4 a0 = *(const uint4*)&Vp [(size_t)(t * 64 + r0) * HDIM + c0];
        uint4 a1 = *(const uint4*)&Vp [(size_t)(t * 64 + r1) * HDIM + c1];
        uint4 b0 = *(const uint4*)&VTp[(size_t)r0 * SEQ + t * 64 + c0];
        uint4 b1 = *(const uint4*)&VTp[(size_t)r1 * SEQ + t * 64 + c1];
        *(uint4*)&Vs [r0 * LDT + c0] = a0;
        *(uint4*)&Vs [r1 * LDT + c1] = a1;
        *(uint4*)&VTs[r0 * LDT + c0] = b0;
        *(uint4*)&VTs[r1 * LDT + c1] = b1;
    };

    // Q tile -> PQs
    #pragma unroll
    for (int i = 0; i < 2; ++i) {
        const int u = tid + i * 256, r = u >> 3, c8 = (u & 7) << 3;
        *(uint4*)&PQs[r * LDT + c8] =
            *(const uint4*)&Qp[(size_t)(s0 + r) * HDIM + c8];
    }
    // ones tile: row 64 = 1, rows 65..79 = 0 (written once)
    #pragma unroll
    for (int i = 0; i < 5; ++i) {
        const int idx = tid + i * 256;
        if (idx < 16 * LDT)
            VTs[64 * LDT + idx] = (idx < LDT) ? (_Float16)1.0f : (_Float16)0.0f;
    }
    stageV(0);
    __syncthreads();

    // hoist Q A-frags (own 16 rows; those rows later hold this wave's P)
    const half8 qa0 = *(const half8*)&PQs[(w * 16 + l15) * LDT + l4 * 8];
    const half8 qa1 = *(const half8*)&PQs[(w * 16 + l15) * LDT + 32 + l4 * 8];

    f32x4 acc_o[5];   // [0..3]: output d-tiles; [4]: softmax denominator
    #pragma unroll
    for (int dt = 0; dt < 5; ++dt) acc_o[dt] = f32x4{0.f, 0.f, 0.f, 0.f};
    float m_i[4] = {-INFINITY, -INFINITY, -INFINITY, -INFINITY};

    const int chi  = l15 >> 3;
    const int hl   = l15 & 7;
    const int rkey = l15 & 7;

    for (int t = 0; t < SEQ / 64; ++t) {
        // ---- QK^T (scores already in exp2 domain: Q pre-scaled) ----
        f32x4 acc_s[4];
        #pragma unroll
        for (int nt = 0; nt < 4; ++nt) acc_s[nt] = f32x4{0.f, 0.f, 0.f, 0.f};
        __builtin_amdgcn_s_setprio(1);
        #pragma unroll
        for (int nt = 0; nt < 4; ++nt) {
            half8 vb0 = *(const half8*)&Vs[(nt * 16 + l15) * LDT + l4 * 8];
            half8 vb1 = *(const half8*)&Vs[(nt * 16 + l15) * LDT + 32 + l4 * 8];
            acc_s[nt] = MFMA16(qa0, vb0, acc_s[nt]);
            acc_s[nt] = MFMA16(qa1, vb1, acc_s[nt]);
        }
        __builtin_amdgcn_s_setprio(0);

        // ---- online softmax (exp2 domain, defer-max) ----
        float mloc[4];
        int needf = 0;
        #pragma unroll
        for (int r = 0; r < 4; ++r) {
            float ml = fmaxf(fmaxf(acc_s[0][r], acc_s[1][r]),
                             fmaxf(acc_s[2][r], acc_s[3][r]));
            #pragma unroll
            for (int off = 1; off < 16; off <<= 1)
                ml = fmaxf(ml, __shfl_xor(ml, off));
            mloc[r] = ml;
            needf |= (ml > m_i[r] + LOG2_THR) ? 1 : 0;
        }
        if (__any(needf)) {
            #pragma unroll
            for (int r = 0; r < 4; ++r) {
                const float mnew = fmaxf(m_i[r], mloc[r]);
                const float corr = __builtin_amdgcn_exp2f(m_i[r] - mnew);
                m_i[r] = mnew;
                #pragma unroll
                for (int dt = 0; dt < 5; ++dt) acc_o[dt][r] *= corr;
            }
        }
        #pragma unroll
        for (int r = 0; r < 4; ++r) {
            const float p0 = __builtin_amdgcn_exp2f(acc_s[0][r] - m_i[r]);
            const float p1 = __builtin_amdgcn_exp2f(acc_s[1][r] - m_i[r]);
            const float p2 = __builtin_amdgcn_exp2f(acc_s[2][r] - m_i[r]);
            const float p3 = __builtin_amdgcn_exp2f(acc_s[3][r] - m_i[r]);
            const int key = (l4 * 4 + r) & 7;
            _Float16* pr = &PQs[(w * 16 + l4 * 4 + r) * LDT];
            pr[(((0 + chi) ^ key) << 3) + hl] = f2h(p0);
            pr[(((2 + chi) ^ key) << 3) + hl] = f2h(p1);
            pr[(((4 + chi) ^ key) << 3) + hl] = f2h(p2);
            pr[(((6 + chi) ^ key) << 3) + hl] = f2h(p3);
        }

        // ---- PV (+ denominator via ones tile, dt==4) ----
        const _Float16* prd = &PQs[(w * 16 + l15) * LDT];
        half8 pa0 = *(const half8*)&prd[((l4 ^ rkey) << 3)];
        half8 pa1 = *(const half8*)&prd[(((4 + l4) ^ rkey) << 3)];
        __builtin_amdgcn_s_setprio(1);
        #pragma unroll
        for (int dt = 0; dt < 5; ++dt) {
            half8 vt0 = *(const half8*)&VTs[(dt * 16 + l15) * LDT + l4 * 8];
            half8 vt1 = *(const half8*)&VTs[(dt * 16 + l15) * LDT + 32 + l4 * 8];
            acc_o[dt] = MFMA16(pa0, vt0, acc_o[dt]);
            acc_o[dt] = MFMA16(pa1, vt1, acc_o[dt]);
        }
        __builtin_amdgcn_s_setprio(0);

        __syncthreads();                   // all reads of Vs/VTs done
        if (t + 1 < SEQ / 64) {
            stageV(t + 1);
            __syncthreads();
        }
    }

    // ---- epilogue: normalize + store fp32 [B][S][H*D] ----
    // denominator = ones-tile result col 0 (lanes l15==0, lane = l4*16)
    #pragma unroll
    for (int r = 0; r < 4; ++r) {
        const float ls  = __shfl(acc_o[4][r], (lane & 48));
        const float inv = 1.f / ls;
        const int s = s0 + w * 16 + l4 * 4 + r;
        float* op = &out[((size_t)(b * SEQ + s)) * HID + h * HDIM + l15];
        op[ 0] = acc_o[0][r] * inv;
        op[16] = acc_o[1][r] * inv;
        op[32] = acc_o[2][r] * inv;
        op[48] = acc_o[3][r] * inv;
    }
}

// ---------------------------------------------------------------------------
extern "C" void kernel_launch(void* const* d_in, const int* in_sizes, int n_in,
                              void* d_out, int out_size, void* d_ws, size_t ws_size,
                              hipStream_t stream) {
    (void)in_sizes; (void)n_in; (void)out_size; (void)ws_size;
    const float* X  = (const float*)d_in[0];
    const float* Wq = (const float*)d_in[1];
    const float* bq = (const float*)d_in[2];
    // d_in[3] = Wk, d_in[4] = bk: unused by the reference output (source bug)
    const float* Wv = (const float*)d_in[5];
    const float* bv = (const float*)d_in[6];
    float* outp = (float*)d_out;

    char* ws = (char*)d_ws;
    _Float16* WTq = (_Float16*)(ws);                    //  2 MB [N][K]
    _Float16* WTv = (_Float16*)(ws + (2u  << 20));      //  2 MB
    _Float16* Qb  = (_Float16*)(ws + (4u  << 20));      //  8 MB [B][H][S][D]
    _Float16* Vb  = (_Float16*)(ws + (12u << 20));      //  8 MB [B][H][S][D]
    _Float16* VTb = (_Float16*)(ws + (20u << 20));      //  8 MB [B][H][D][S]

    conv_wt_kernel<<<dim3(16, 16, 2), 256, 0, stream>>>(Wq, WTq, Wv, WTv);
    proj_kernel<<<1024, 256, 0, stream>>>(X, WTq, WTv, bq, bv, Qb, Vb, VTb);
    attn_kernel<<<1024, 256, 0, stream>>>(Qb, Vb, VTb, outp);
}

// Round 7
// 201.954 us; speedup vs baseline: 1.6059x; 1.1337x over previous
//
#include <hip/hip_runtime.h>
#include <math.h>

// MultiHeadSelfAttention: B=2, S=2048, E=1024, H=16, D=64
// Reference computes Q@V^T (source bug, K unused) -> softmax -> @V.
// Round 7: proj rebuilt on m97 recipe: BM=256 tile, global_load_lds(16B)
// staging into double-buffered LDS with pre-swizzled global sources
// (chunk ^= row&7 per 64-half group), 64 MFMA / 24 ds_read_b128 per
// wave-iter. attn unchanged from R6 (98us, clean counters).

constexpr int BATCH = 2;
constexpr int SEQ   = 2048;
constexpr int EMB   = 1024;
constexpr int NHEAD = 16;
constexpr int HDIM  = 64;
constexpr int HID   = 1024;

typedef __attribute__((ext_vector_type(8))) _Float16 half8;
typedef __attribute__((ext_vector_type(4))) float    f32x4;

#define MFMA16(a, b, c) __builtin_amdgcn_mfma_f32_16x16x32_f16((a), (b), (c), 0, 0, 0)

// attn LDS leading dim (halves): 80 -> frag reads 2-way (free).
constexpr int LDT = 80;

// 1/sqrt(64) * log2(e): scores land directly in exp2 domain (folded into Q).
#define QK_SCALE 0.18033688011112042f
// defer-max threshold in log2 units: P <= 2^11 = 2048, safe in fp16.
#define LOG2_THR 11.0f

__device__ __forceinline__ _Float16 f2h(float f) { return (_Float16)f; }

// global -> LDS async copy, 16B per lane. LDS dest must be the wave-uniform
// base (HW adds lane*16); global src is per-lane.
__device__ __forceinline__ void gl16(const _Float16* g, _Float16* l) {
    __builtin_amdgcn_global_load_lds(
        (const __attribute__((address_space(1))) void*)g,
        (__attribute__((address_space(3))) void*)l, 16, 0, 0);
}

// ---------------------------------------------------------------------------
// conv_x: X fp32 -> Xz fp16, chunk-swizzled within each 64-half k-group:
// Xz[m][g*64 + c*8 + e] = X[m][g*64 + (c^(m&7))*8 + e]
// so a LINEAR gload_lds copy of a row slice gives swizzled LDS; proj reads
// chunk c at LDS chunk c^(r&7).
// ---------------------------------------------------------------------------
__global__ __launch_bounds__(256) void conv_x_kernel(
    const float* __restrict__ X, _Float16* __restrict__ Xz)
{
    const int idx = blockIdx.x * 256 + threadIdx.x;  // chunk id (8 halves)
    const int m  = idx >> 7;                         // 128 chunks per row
    const int cg = idx & 127;
    const int g8 = cg >> 3;                          // 64-half group
    const int c  = cg & 7;                           // dest chunk
    const int cs = c ^ (m & 7);                      // src chunk
    const float* s = &X[(size_t)m * EMB + g8 * 64 + cs * 8];
    const float4 a = *(const float4*)s;
    const float4 b = *(const float4*)(s + 4);
    union { uint4 q; _Float16 e[8]; } p;
    p.e[0] = f2h(a.x); p.e[1] = f2h(a.y); p.e[2] = f2h(a.z); p.e[3] = f2h(a.w);
    p.e[4] = f2h(b.x); p.e[5] = f2h(b.y); p.e[6] = f2h(b.z); p.e[7] = f2h(b.w);
    *(uint4*)&Xz[(size_t)m * EMB + g8 * 64 + c * 8] = p.q;
}

// ---------------------------------------------------------------------------
// conv_wt: W [K][N] fp32 -> WT [N][K] fp16, transposed AND chunk-swizzled
// (key = n&7 within each 64-half k-group). Both weights in one launch (z).
// ---------------------------------------------------------------------------
__global__ __launch_bounds__(256) void conv_wt_kernel(
    const float* __restrict__ W0, _Float16* __restrict__ WT0,
    const float* __restrict__ W1, _Float16* __restrict__ WT1)
{
    const float*  W  = blockIdx.z ? W1  : W0;
    _Float16*     WT = blockIdx.z ? WT1 : WT0;
    __shared__ _Float16 T[64 * 68];
    const int tid = threadIdx.x;
    const int n0 = blockIdx.x * 64;
    const int k0 = blockIdx.y * 64;   // one swizzle group per k-tile

    #pragma unroll
    for (int i = 0; i < 4; ++i) {
        const int u = tid + i * 256;
        const int r = u >> 4;              // k row
        const int c4 = (u & 15) << 2;      // n col
        const float4 v = *(const float4*)&W[(size_t)(k0 + r) * HID + n0 + c4];
        T[r * 68 + c4 + 0] = f2h(v.x);
        T[r * 68 + c4 + 1] = f2h(v.y);
        T[r * 68 + c4 + 2] = f2h(v.z);
        T[r * 68 + c4 + 3] = f2h(v.w);
    }
    __syncthreads();

    union Pack { uint4 q; _Float16 e[8]; };
    #pragma unroll
    for (int i = 0; i < 2; ++i) {
        const int u = tid + i * 256;
        const int n = u >> 3;
        const int cdst = u & 7;                       // dest chunk
        const int ks = ((cdst ^ (n & 7)) << 3);       // src k offset (swizzle)
        Pack p;
        #pragma unroll
        for (int j = 0; j < 8; ++j) p.e[j] = T[(ks + j) * 68 + n];
        *(uint4*)&WT[(size_t)(n0 + n) * EMB + k0 + (cdst << 3)] = p.q;
    }
}

// ---------------------------------------------------------------------------
// proj: Q = (X@Wq + bq)*QK_SCALE, V = X@Wv + bv -> fp16 [B][H][S][D] (+VT).
// BM=256, BN=64(=head), BK=64, 4 waves x (64 rows x 64 cols x {q,v}).
// Double-buffered LDS (96KB static), global_load_lds staging, 1 barrier/iter.
// Grid 256 (16 mgrp x 16 h), m-grouped XCD remap.
// ---------------------------------------------------------------------------
__global__ __launch_bounds__(256, 1) void proj_kernel(
    const _Float16* __restrict__ Xz, const _Float16* __restrict__ WTq,
    const _Float16* __restrict__ WTv, const float* __restrict__ bq,
    const float* __restrict__ bv, _Float16* __restrict__ Qo,
    _Float16* __restrict__ Vo, _Float16* __restrict__ VTo)
{
    __shared__ __align__(16) _Float16 Xs[2 * 256 * 64];   // 64 KB
    __shared__ __align__(16) _Float16 Wqs[2 * 64 * 64];   // 16 KB
    __shared__ __align__(16) _Float16 Wvs[2 * 64 * 64];   // 16 KB

    const int tid  = threadIdx.x;
    const int lane = tid & 63;
    const int w    = tid >> 6;
    const int l15  = lane & 15;
    const int l4   = lane >> 4;
    // XCD remap: 32 blocks/XCD = 2 m-groups x 16 heads -> X panels L2-local.
    const int wg  = blockIdx.x;
    const int nid = (wg & 7) * 32 + (wg >> 3);
    const int mg  = nid >> 4;
    const int h   = nid & 15;
    const int m0  = mg * 256;
    const int n0  = h * HDIM;

    const int lr = lane >> 3;          // staging: row-in-8 block
    const int lc = (lane & 7) << 3;    // staging: chunk offset (halves)

    f32x4 aq[4][4], av[4][4];
    #pragma unroll
    for (int mt = 0; mt < 4; ++mt)
        #pragma unroll
        for (int nt = 0; nt < 4; ++nt) {
            aq[mt][nt] = f32x4{0.f, 0.f, 0.f, 0.f};
            av[mt][nt] = f32x4{0.f, 0.f, 0.f, 0.f};
        }

    auto stage = [&](int k0, int b) {
        _Float16* xb = &Xs[b * (256 * 64)];
        const _Float16* gx = Xz + (size_t)(m0 + w * 64) * EMB + k0;
        #pragma unroll
        for (int i = 0; i < 8; ++i)
            gl16(&gx[(size_t)(i * 8 + lr) * EMB + lc], &xb[(w * 64 + i * 8) * 64]);
        _Float16* qb = &Wqs[b * (64 * 64)];
        _Float16* vb = &Wvs[b * (64 * 64)];
        const _Float16* gq = WTq + (size_t)(n0 + w * 16) * EMB + k0;
        const _Float16* gv = WTv + (size_t)(n0 + w * 16) * EMB + k0;
        #pragma unroll
        for (int i = 0; i < 2; ++i) {
            gl16(&gq[(size_t)(i * 8 + lr) * EMB + lc], &qb[(w * 16 + i * 8) * 64]);
            gl16(&gv[(size_t)(i * 8 + lr) * EMB + lc], &vb[(w * 16 + i * 8) * 64]);
        }
    };

    stage(0, 0);
    __syncthreads();

    int buf = 0;
    const int key = l15 & 7;
    for (int t = 0; t < 16; ++t) {
        if (t < 15) stage((t + 1) * 64, buf ^ 1);   // in flight under compute

        const _Float16* xb = &Xs[buf * (256 * 64)];
        const _Float16* qb = &Wqs[buf * (64 * 64)];
        const _Float16* vb = &Wvs[buf * (64 * 64)];
        __builtin_amdgcn_s_setprio(1);
        #pragma unroll
        for (int kd = 0; kd < 2; ++kd) {
            const int ch = ((kd * 4 + l4) ^ key) << 3;   // swizzled chunk
            half8 xa[4], wq[4], wv[4];
            #pragma unroll
            for (int mt = 0; mt < 4; ++mt)
                xa[mt] = *(const half8*)&xb[(w * 64 + mt * 16 + l15) * 64 + ch];
            #pragma unroll
            for (int nt = 0; nt < 4; ++nt) {
                wq[nt] = *(const half8*)&qb[(nt * 16 + l15) * 64 + ch];
                wv[nt] = *(const half8*)&vb[(nt * 16 + l15) * 64 + ch];
            }
            #pragma unroll
            for (int mt = 0; mt < 4; ++mt)
                #pragma unroll
                for (int nt = 0; nt < 4; ++nt) {
                    aq[mt][nt] = MFMA16(xa[mt], wq[nt], aq[mt][nt]);
                    av[mt][nt] = MFMA16(xa[mt], wv[nt], av[mt][nt]);
                }
        }
        __builtin_amdgcn_s_setprio(0);
        __syncthreads();   // compiler drains vmcnt here (loads had full compute)
        buf ^= 1;
    }

    // ---- epilogue: bias, Q pre-scale, V + coalesced VT via LDS bounce ----
    constexpr int LV = 65;
    _Float16* Vlds = Xs;               // 256*65 halves = 33 KB, fits
    const int bb = m0 >> 11;
    const int sb = m0 & (SEQ - 1);
    const int bh = bb * NHEAD + h;

    #pragma unroll
    for (int nt = 0; nt < 4; ++nt) {
        const int d = nt * 16 + l15;
        const float bqv = bq[n0 + d];
        const float bvv = bv[n0 + d];
        #pragma unroll
        for (int mt = 0; mt < 4; ++mt)
            #pragma unroll
            for (int r = 0; r < 4; ++r) {
                const int sl = w * 64 + mt * 16 + l4 * 4 + r;
                const int s  = sb + sl;
                const _Float16 vh = f2h(av[mt][nt][r] + bvv);
                Qo[((size_t)bh * SEQ + s) * HDIM + d] =
                    f2h((aq[mt][nt][r] + bqv) * QK_SCALE);
                Vo[((size_t)bh * SEQ + s) * HDIM + d] = vh;
                Vlds[sl * LV + d] = vh;
            }
    }
    __syncthreads();

    union PK { uint4 q; _Float16 e[8]; };
    #pragma unroll
    for (int i = 0; i < 8; ++i) {
        const int cix = tid + i * 256;     // 0..2047: 64 d x 32 s-chunks
        const int d  = cix >> 5;
        const int sc = (cix & 31) << 3;
        PK p;
        #pragma unroll
        for (int j = 0; j < 8; ++j) p.e[j] = Vlds[(sc + j) * LV + d];
        *(uint4*)&VTo[((size_t)bh * HDIM + d) * SEQ + sb + sc] = p.q;
    }
}

// ---------------------------------------------------------------------------
// attn: unchanged from R6. scores = Q@V^T (Q pre-scaled, exp2 domain),
// online softmax + defer-max, denominator via ones-row tile (5th PV MFMA).
// ---------------------------------------------------------------------------
__global__ __launch_bounds__(256) void attn_kernel(
    const _Float16* __restrict__ Qw, const _Float16* __restrict__ Vw,
    const _Float16* __restrict__ VTw, float* __restrict__ out)
{
    __shared__ __align__(16) _Float16 PQs[64 * LDT];  // Q then P (overlay)
    __shared__ __align__(16) _Float16 Vs[64 * LDT];
    __shared__ __align__(16) _Float16 VTs[80 * LDT];  // rows 64..79: ones tile

    const int tid  = threadIdx.x;
    const int lane = tid & 63;
    const int w    = tid >> 6;
    const int l15  = lane & 15;
    const int l4   = lane >> 4;
    const int wg = blockIdx.x;
    const int nw = (wg & 7) * 128 + (wg >> 3);
    const int bh = nw >> 5;
    const int qb = nw & 31;
    const int b  = bh >> 4;
    const int h  = bh & (NHEAD - 1);
    const int s0 = qb * 64;

    const _Float16* Qp  = Qw  + (size_t)bh * SEQ * HDIM;
    const _Float16* Vp  = Vw  + (size_t)bh * SEQ * HDIM;
    const _Float16* VTp = VTw + (size_t)bh * HDIM * SEQ;

    auto stageV = [&](int t) {
        const int u0 = tid,       r0 = u0 >> 3, c0 = (u0 & 7) << 3;
        const int u1 = tid + 256, r1 = u1 >> 3, c1 = (u1 & 7) << 3;
        uint4 a0 = *(const uint4*)&Vp [(size_t)(t * 64 + r0) * HDIM + c0];
        uint4 a1 = *(const uint4*)&Vp [(size_t)(t * 64 + r1) * HDIM + c1];
        uint4 b0 = *(const uint4*)&VTp[(size_t)r0 * SEQ + t * 64 + c0];
        uint4 b1 = *(const uint4*)&VTp[(size_t)r1 * SEQ + t * 64 + c1];
        *(uint4*)&Vs [r0 * LDT + c0] = a0;
        *(uint4*)&Vs [r1 * LDT + c1] = a1;
        *(uint4*)&VTs[r0 * LDT + c0] = b0;
        *(uint4*)&VTs[r1 * LDT + c1] = b1;
    };

    #pragma unroll
    for (int i = 0; i < 2; ++i) {
        const int u = tid + i * 256, r = u >> 3, c8 = (u & 7) << 3;
        *(uint4*)&PQs[r * LDT + c8] =
            *(const uint4*)&Qp[(size_t)(s0 + r) * HDIM + c8];
    }
    #pragma unroll
    for (int i = 0; i < 5; ++i) {
        const int idx = tid + i * 256;
        if (idx < 16 * LDT)
            VTs[64 * LDT + idx] = (idx < LDT) ? (_Float16)1.0f : (_Float16)0.0f;
    }
    stageV(0);
    __syncthreads();

    const half8 qa0 = *(const half8*)&PQs[(w * 16 + l15) * LDT + l4 * 8];
    const half8 qa1 = *(const half8*)&PQs[(w * 16 + l15) * LDT + 32 + l4 * 8];

    f32x4 acc_o[5];
    #pragma unroll
    for (int dt = 0; dt < 5; ++dt) acc_o[dt] = f32x4{0.f, 0.f, 0.f, 0.f};
    float m_i[4] = {-INFINITY, -INFINITY, -INFINITY, -INFINITY};

    const int chi  = l15 >> 3;
    const int hl   = l15 & 7;
    const int rkey = l15 & 7;

    for (int t = 0; t < SEQ / 64; ++t) {
        f32x4 acc_s[4];
        #pragma unroll
        for (int nt = 0; nt < 4; ++nt) acc_s[nt] = f32x4{0.f, 0.f, 0.f, 0.f};
        __builtin_amdgcn_s_setprio(1);
        #pragma unroll
        for (int nt = 0; nt < 4; ++nt) {
            half8 vb0 = *(const half8*)&Vs[(nt * 16 + l15) * LDT + l4 * 8];
            half8 vb1 = *(const half8*)&Vs[(nt * 16 + l15) * LDT + 32 + l4 * 8];
            acc_s[nt] = MFMA16(qa0, vb0, acc_s[nt]);
            acc_s[nt] = MFMA16(qa1, vb1, acc_s[nt]);
        }
        __builtin_amdgcn_s_setprio(0);

        float mloc[4];
        int needf = 0;
        #pragma unroll
        for (int r = 0; r < 4; ++r) {
            float ml = fmaxf(fmaxf(acc_s[0][r], acc_s[1][r]),
                             fmaxf(acc_s[2][r], acc_s[3][r]));
            #pragma unroll
            for (int off = 1; off < 16; off <<= 1)
                ml = fmaxf(ml, __shfl_xor(ml, off));
            mloc[r] = ml;
            needf |= (ml > m_i[r] + LOG2_THR) ? 1 : 0;
        }
        if (__any(needf)) {
            #pragma unroll
            for (int r = 0; r < 4; ++r) {
                const float mnew = fmaxf(m_i[r], mloc[r]);
                const float corr = __builtin_amdgcn_exp2f(m_i[r] - mnew);
                m_i[r] = mnew;
                #pragma unroll
                for (int dt = 0; dt < 5; ++dt) acc_o[dt][r] *= corr;
            }
        }
        #pragma unroll
        for (int r = 0; r < 4; ++r) {
            const float p0 = __builtin_amdgcn_exp2f(acc_s[0][r] - m_i[r]);
            const float p1 = __builtin_amdgcn_exp2f(acc_s[1][r] - m_i[r]);
            const float p2 = __builtin_amdgcn_exp2f(acc_s[2][r] - m_i[r]);
            const float p3 = __builtin_amdgcn_exp2f(acc_s[3][r] - m_i[r]);
            const int key = (l4 * 4 + r) & 7;
            _Float16* pr = &PQs[(w * 16 + l4 * 4 + r) * LDT];
            pr[(((0 + chi) ^ key) << 3) + hl] = f2h(p0);
            pr[(((2 + chi) ^ key) << 3) + hl] = f2h(p1);
            pr[(((4 + chi) ^ key) << 3) + hl] = f2h(p2);
            pr[(((6 + chi) ^ key) << 3) + hl] = f2h(p3);
        }

        const _Float16* prd = &PQs[(w * 16 + l15) * LDT];
        half8 pa0 = *(const half8*)&prd[((l4 ^ rkey) << 3)];
        half8 pa1 = *(const half8*)&prd[(((4 + l4) ^ rkey) << 3)];
        __builtin_amdgcn_s_setprio(1);
        #pragma unroll
        for (int dt = 0; dt < 5; ++dt) {
            half8 vt0 = *(const half8*)&VTs[(dt * 16 + l15) * LDT + l4 * 8];
            half8 vt1 = *(const half8*)&VTs[(dt * 16 + l15) * LDT + 32 + l4 * 8];
            acc_o[dt] = MFMA16(pa0, vt0, acc_o[dt]);
            acc_o[dt] = MFMA16(pa1, vt1, acc_o[dt]);
        }
        __builtin_amdgcn_s_setprio(0);

        __syncthreads();
        if (t + 1 < SEQ / 64) {
            stageV(t + 1);
            __syncthreads();
        }
    }

    #pragma unroll
    for (int r = 0; r < 4; ++r) {
        const float ls  = __shfl(acc_o[4][r], (lane & 48));
        const float inv = 1.f / ls;
        const int s = s0 + w * 16 + l4 * 4 + r;
        float* op = &out[((size_t)(b * SEQ + s)) * HID + h * HDIM + l15];
        op[ 0] = acc_o[0][r] * inv;
        op[16] = acc_o[1][r] * inv;
        op[32] = acc_o[2][r] * inv;
        op[48] = acc_o[3][r] * inv;
    }
}

// ---------------------------------------------------------------------------
extern "C" void kernel_launch(void* const* d_in, const int* in_sizes, int n_in,
                              void* d_out, int out_size, void* d_ws, size_t ws_size,
                              hipStream_t stream) {
    (void)in_sizes; (void)n_in; (void)out_size; (void)ws_size;
    const float* X  = (const float*)d_in[0];
    const float* Wq = (const float*)d_in[1];
    const float* bq = (const float*)d_in[2];
    // d_in[3] = Wk, d_in[4] = bk: unused by the reference output (source bug)
    const float* Wv = (const float*)d_in[5];
    const float* bv = (const float*)d_in[6];
    float* outp = (float*)d_out;

    char* ws = (char*)d_ws;
    _Float16* Xz  = (_Float16*)(ws);                    //  8 MB [4096][1024] swz
    _Float16* WTq = (_Float16*)(ws + (8u  << 20));      //  2 MB [N][K] swz
    _Float16* WTv = (_Float16*)(ws + (10u << 20));      //  2 MB
    _Float16* Qb  = (_Float16*)(ws + (12u << 20));      //  8 MB [B][H][S][D]
    _Float16* Vb  = (_Float16*)(ws + (20u << 20));      //  8 MB [B][H][S][D]
    _Float16* VTb = (_Float16*)(ws + (28u << 20));      //  8 MB [B][H][D][S]

    conv_x_kernel<<<2048, 256, 0, stream>>>(X, Xz);
    conv_wt_kernel<<<dim3(16, 16, 2), 256, 0, stream>>>(Wq, WTq, Wv, WTv);
    proj_kernel<<<256, 256, 0, stream>>>(Xz, WTq, WTv, bq, bv, Qb, Vb, VTb);
    attn_kernel<<<1024, 256, 0, stream>>>(Qb, Vb, VTb, outp);
}